// Round 7
// baseline (627.638 us; speedup 1.0000x reference)
//
#include <hip/hip_runtime.h>
#include <hip/hip_bf16.h>

// Problem constants (BayesianLinear): IN_F=64, OUT_F=32, N=2080, B*S=16384
#define IN_F  64
#define OUT_F 32
#define NV    2080           // N
#define NPAD  2176           // 17*128
#define MM    16384          // tokens
#define KK    2080           // contraction dim
#define NBN   17             // column tiles

typedef __attribute__((ext_vector_type(4))) float f32x4;
typedef __bf16 bf16x8 __attribute__((ext_vector_type(8)));

using gas_ptr = const __attribute__((address_space(1))) void*;
using lds_ptr = __attribute__((address_space(3))) void*;

// ---------------------------------------------------------------------------
// Kernel 1: build L (bf16, row-major [NPAD][KK]); rows >= NV are zero.
// ---------------------------------------------------------------------------
__global__ __launch_bounds__(256) void build_L_k(const float* __restrict__ cov,
                                                 const float* __restrict__ logvar,
                                                 __hip_bfloat16* __restrict__ LB) {
    const int idx = blockIdx.x * 256 + threadIdx.x;   // over NPAD*KK
    const int m = idx / KK;
    const int k = idx - m * KK;
    float v = 0.0f;
    if (m < NV) {
        if (k < m)       v = cov[(size_t)(m * (m - 1) / 2) + k];
        else if (k == m) v = expf(0.5f * logvar[m]);
    }
    LB[idx] = __float2bfloat16(v);
}

// ---------------------------------------------------------------------------
// Kernel 2: fused cvt + GEMM + in-lane x-contraction.
// Grid TRANSPOSED vs R6: bn on blockIdx.x (fast) so the 17 blocks sharing one
// 1MB fp32 eps tile dispatch adjacently -> tile is HBM-fetched once, L2/L3-hit
// by the rest.  A (eps fp32) -> registers -> bf16 -> ds_write into the proven
// 0-conflict swizzled layout, with DISTANCE-2 prefetch: at iter kb we ds_write
// regs loaded a full iteration earlier (no vmcnt stall), then issue loads for
// kb+2.  Two named register sets, manually 2x-unrolled loop (tile t lives in
// set t&1).  B (L bf16) stays on global_load_lds.  kblocks=min(65,4bn+4).
// ---------------------------------------------------------------------------
__global__ __launch_bounds__(256, 4) void gemm_zl_k(const float* __restrict__ A,
                                                    const __hip_bfloat16* __restrict__ BT,
                                                    const float* __restrict__ loc,
                                                    const float* __restrict__ x,
                                                    float* __restrict__ Ypart) {
    __shared__ __align__(16) __hip_bfloat16 As[2][128 * 32];
    __shared__ __align__(16) __hip_bfloat16 Bs[2][128 * 32];
    __shared__ float xs[128][4];

    const int tid  = threadIdx.x;
    const int bn   = (NBN - 1) - blockIdx.x; // 0..16, heavy (bn=16) first in each group
    const int bm   = blockIdx.y;             // 0..127 (M tiles)
    const int wave = tid >> 6;
    const int lane = tid & 63;
    const int quad = lane >> 4;              // 0..3
    const int r16  = lane & 15;

    const int kblocks = min(KK / 32, 4 * bn + 4);   // triangular truncation

    // stage xs: weight for h = 4bn-1+c; bias (1.0) at bn==0,c==0; 0 if h invalid
    {
        const int tl = tid >> 1;
        const int cc = (tid & 1) * 2;
#pragma unroll
        for (int c = cc; c < cc + 2; c++) {
            const int h = 4 * bn - 1 + c;
            float w = 0.0f;
            if (bn == 0 && c == 0)          w = 1.0f;
            else if (h >= 0 && h < IN_F)    w = x[(size_t)(bm * 128 + tl) * IN_F + h];
            xs[tl][c] = w;
        }
    }

    const float*          Ag = A  + (size_t)bm * 128 * KK;   // fp32 eps tile
    const __hip_bfloat16* Bg = BT + (size_t)bn * 128 * KK;

    // chunk mapping: 512 chunks; chunk c -> slot (c>>2, c&3), holding global
    // part (c&3)^((row>>1)&3); offset row*KK + part*8 elements.
    const int c0 = tid, c1 = tid + 256;
    const int ar0 = c0 >> 2, ap0 = (c0 & 3) ^ ((ar0 >> 1) & 3);
    const int ar1 = c1 >> 2, ap1 = (c1 & 3) ^ ((ar1 >> 1) & 3);
    const size_t gofs0 = (size_t)ar0 * KK + ap0 * 8;
    const size_t gofs1 = (size_t)ar1 * KK + ap1 * 8;

    f32x4 acc[2][8];
#pragma unroll
    for (int i = 0; i < 2; i++)
#pragma unroll
        for (int j = 0; j < 8; j++) acc[i][j] = f32x4{0.f, 0.f, 0.f, 0.f};

    // fragment-read LDS offsets (elements), swizzled — identical to R2/R5
    int aofs[2], bofs[8];
#pragma unroll
    for (int i = 0; i < 2; i++) {
        const int arow = 32 * wave + 16 * i + r16;
        aofs[i] = arow * 32 + (quad ^ ((arow >> 1) & 3)) * 8;
    }
#pragma unroll
    for (int j = 0; j < 8; j++) {
        const int brow = 16 * j + r16;
        bofs[j] = brow * 32 + (quad ^ ((brow >> 1) & 3)) * 8;
    }

    // two A register sets: tile t lives in set (t&1)
    f32x4 sa0, sa1, sa2, sa3;   // set 0 (even tiles)
    f32x4 sb0, sb1, sb2, sb3;   // set 1 (odd tiles)

    // --- prologue: tile0 -> LDS buf0 (via set0), tile1 -> set1, B(0) glds ---
    {
        sa0 = *(const f32x4*)(Ag + gofs0);
        sa1 = *(const f32x4*)(Ag + gofs0 + 4);
        sa2 = *(const f32x4*)(Ag + gofs1);
        sa3 = *(const f32x4*)(Ag + gofs1 + 4);
        __builtin_amdgcn_global_load_lds((gas_ptr)(Bg + gofs0), (lds_ptr)(&Bs[0][0] + c0 * 8), 16, 0, 0);
        __builtin_amdgcn_global_load_lds((gas_ptr)(Bg + gofs1), (lds_ptr)(&Bs[0][0] + c1 * 8), 16, 0, 0);
        bf16x8 w0, w1;
#pragma unroll
        for (int q = 0; q < 4; q++) {
            w0[q] = (__bf16)sa0[q]; w0[4 + q] = (__bf16)sa1[q];
            w1[q] = (__bf16)sa2[q]; w1[4 + q] = (__bf16)sa3[q];
        }
        *(bf16x8*)(&As[0][0] + c0 * 8) = w0;
        *(bf16x8*)(&As[0][0] + c1 * 8) = w1;
        if (1 < kblocks) {
            sb0 = *(const f32x4*)(Ag + 32 + gofs0);
            sb1 = *(const f32x4*)(Ag + 32 + gofs0 + 4);
            sb2 = *(const f32x4*)(Ag + 32 + gofs1);
            sb3 = *(const f32x4*)(Ag + 32 + gofs1 + 4);
        }
    }

    // body: at iter KB (buffer CUR): ds_write tile KB+1 (regs W*, loaded one
    // iter ago), glds B(KB+1); issue loads of tile KB+2 into L*; compute.
#define KSTEP(KB, CUR, W0, W1, W2, W3, L0, L1, L2, L3)                          \
    {                                                                           \
        __syncthreads();                                                        \
        if ((KB) + 1 < kblocks) {                                               \
            bf16x8 w0, w1;                                                      \
            _Pragma("unroll")                                                   \
            for (int q = 0; q < 4; q++) {                                       \
                w0[q] = (__bf16)W0[q]; w0[4 + q] = (__bf16)W1[q];               \
                w1[q] = (__bf16)W2[q]; w1[4 + q] = (__bf16)W3[q];               \
            }                                                                   \
            *(bf16x8*)(&As[(CUR) ^ 1][0] + c0 * 8) = w0;                        \
            *(bf16x8*)(&As[(CUR) ^ 1][0] + c1 * 8) = w1;                        \
            const size_t k1 = (size_t)((KB) + 1) * 32;                          \
            __builtin_amdgcn_global_load_lds((gas_ptr)(Bg + k1 + gofs0),        \
                (lds_ptr)(&Bs[(CUR) ^ 1][0] + c0 * 8), 16, 0, 0);               \
            __builtin_amdgcn_global_load_lds((gas_ptr)(Bg + k1 + gofs1),        \
                (lds_ptr)(&Bs[(CUR) ^ 1][0] + c1 * 8), 16, 0, 0);               \
        }                                                                       \
        if ((KB) + 2 < kblocks) {                                               \
            const size_t k2 = (size_t)((KB) + 2) * 32;                          \
            L0 = *(const f32x4*)(Ag + k2 + gofs0);                              \
            L1 = *(const f32x4*)(Ag + k2 + gofs0 + 4);                          \
            L2 = *(const f32x4*)(Ag + k2 + gofs1);                              \
            L3 = *(const f32x4*)(Ag + k2 + gofs1 + 4);                          \
        }                                                                       \
        bf16x8 af[2], bfr[8];                                                   \
        _Pragma("unroll")                                                       \
        for (int i = 0; i < 2; i++) af[i]  = *(const bf16x8*)(&As[CUR][0] + aofs[i]); \
        _Pragma("unroll")                                                       \
        for (int j = 0; j < 8; j++) bfr[j] = *(const bf16x8*)(&Bs[CUR][0] + bofs[j]); \
        _Pragma("unroll")                                                       \
        for (int i = 0; i < 2; i++)                                             \
            _Pragma("unroll")                                                   \
            for (int j = 0; j < 8; j++)                                         \
                acc[i][j] = __builtin_amdgcn_mfma_f32_16x16x32_bf16(af[i], bfr[j], acc[i][j], 0, 0, 0); \
    }

    for (int kb = 0; kb < kblocks; kb += 2) {
        // even iter: compute buf0; write tile kb+1 (set1); load tile kb+2 (set0)
        KSTEP(kb, 0, sb0, sb1, sb2, sb3, sa0, sa1, sa2, sa3);
        if (kb + 1 < kblocks) {
            // odd iter: compute buf1; write tile kb+2 (set0); load tile kb+3 (set1)
            KSTEP(kb + 1, 1, sa0, sa1, sa2, sa3, sb0, sb1, sb2, sb3);
        }
    }
#undef KSTEP

    // in-lane epilogue.  C/D layout (m89): col=lane&15 (per 16-tile), row=quad*4+reg
    float locv[8];
#pragma unroll
    for (int j = 0; j < 8; j++) {
        const int col = bn * 128 + 16 * j + r16;
        locv[j] = (col < NV) ? loc[col] : 0.0f;
    }

    float* yp = Ypart + ((size_t)bn * MM + (size_t)bm * 128) * OUT_F;
#pragma unroll
    for (int i = 0; i < 2; i++) {
#pragma unroll
        for (int r = 0; r < 4; r++) {
            const int tl = 32 * wave + 16 * i + 4 * quad + r;
            float v0 = 0.0f, v1 = 0.0f;
#pragma unroll
            for (int c = 0; c < 4; c++) {
                const float w = xs[tl][c];
                v0 += w * (acc[i][2 * c][r]     + locv[2 * c]);
                v1 += w * (acc[i][2 * c + 1][r] + locv[2 * c + 1]);
            }
            yp[(size_t)tl * OUT_F + r16]      = v0;
            yp[(size_t)tl * OUT_F + 16 + r16] = v1;
        }
    }
}

// ---------------------------------------------------------------------------
// Kernel 3: reduce 17 partials -> y
// ---------------------------------------------------------------------------
__global__ __launch_bounds__(256) void reduce_y_k(const float4* __restrict__ yp,
                                                  float4* __restrict__ y) {
    const size_t i = (size_t)blockIdx.x * 256 + threadIdx.x;   // MM*32/4
    float4 s = yp[i];
#pragma unroll
    for (int b = 1; b < NBN; b++) {
        float4 v = yp[i + (size_t)b * (MM * OUT_F / 4)];
        s.x += v.x; s.y += v.y; s.z += v.z; s.w += v.w;
    }
    y[i] = s;
}

// ---------------------------------------------------------------------------
extern "C" void kernel_launch(void* const* d_in, const int* in_sizes, int n_in,
                              void* d_out, int out_size, void* d_ws, size_t ws_size,
                              hipStream_t stream) {
    const float* x      = (const float*)d_in[0];
    const float* eps    = (const float*)d_in[1];
    const float* loc    = (const float*)d_in[2];
    const float* logvar = (const float*)d_in[3];
    const float* cov    = (const float*)d_in[4];
    float* y = (float*)d_out;

    char* ws = (char*)d_ws;
    __hip_bfloat16* LB    = (__hip_bfloat16*)ws;                             // NPAD*KK bf16 (9.1 MB)
    float*          Ypart = (float*)(ws + (size_t)NPAD * KK * 2);            // 17*MM*32 fp32 (35.7 MB)

    build_L_k<<<(NPAD * KK) / 256, 256, 0, stream>>>(cov, logvar, LB);
    gemm_zl_k<<<dim3(NBN, MM / 128), 256, 0, stream>>>(eps, LB, loc, x, Ypart);
    reduce_y_k<<<(MM * OUT_F / 4) / 256, 256, 0, stream>>>((const float4*)Ypart, (float4*)y);
}